// Round 1
// baseline (520.187 us; speedup 1.0000x reference)
//
#include <hip/hip_runtime.h>

#define D 128
#define BK 32

// K0: gvec = globals @ W3 + b3   (1x128 @ 128x128)
__global__ void k_gproj(const float* __restrict__ g, const float* __restrict__ W3,
                        const float* __restrict__ b3, float* __restrict__ gvec) {
  const int j = threadIdx.x;
  float acc = b3[j];
  for (int k = 0; k < D; ++k) acc = fmaf(g[k], W3[k * D + j], acc);
  gvec[j] = acc;
}

// K1: degree histograms (int atomics, avg degree 6.4 -> low contention)
__global__ void k_degrees(const int* __restrict__ snd, const int* __restrict__ rcv,
                          int* __restrict__ cs, int* __restrict__ cr, int E) {
  const int e = blockIdx.x * blockDim.x + threadIdx.x;
  if (e < E) {
    atomicAdd(cs + snd[e], 1);
    atomicAdd(cr + rcv[e], 1);
  }
}

// K2: single-block exclusive scan in THREAD-OWNERSHIP order (thread t owns rows
// t, t+1024, ...). Offsets only need to be disjoint ranges -- segment order is
// irrelevant for a sum -- and this keeps both passes fully coalesced.
__global__ void k_scan(const int* __restrict__ cnt, int* __restrict__ off,
                       int* __restrict__ cursor, int n) {
  __shared__ int part[1024];
  const int t = threadIdx.x;
  int s = 0;
  for (int r = t; r < n; r += 1024) s += cnt[r];
  part[t] = s;
  __syncthreads();
  for (int st = 1; st < 1024; st <<= 1) {
    int v = (t >= st) ? part[t - st] : 0;
    __syncthreads();
    part[t] += v;
    __syncthreads();
  }
  int running = (t == 0) ? 0 : part[t - 1];
  for (int r = t; r < n; r += 1024) {
    off[r] = running;
    cursor[r] = running;
    running += cnt[r];
  }
}

// K3: CSR fill (sort edges by receiver via atomic cursors)
__global__ void k_fill(const int* __restrict__ snd, const int* __restrict__ rcv,
                       int* __restrict__ cursor, int* __restrict__ srt, int E) {
  const int e = blockIdx.x * blockDim.x + threadIdx.x;
  if (e < E) {
    const int p = atomicAdd(cursor + rcv[e], 1);
    srt[p] = snd[e];
  }
}

// K4: fused dual GEMM. gridDim.y==0: outH = A@W1 + b1 + gvec (pre-relu partial h)
//                      gridDim.y==1: conv = (A@W2 + b2) * rsqrt(max(send_deg,1))
// 128x128 output tile / block, 256 threads, 8x8 register microtile (split 4+4
// across each 64-half to keep LDS reads 2-way-or-better on banks).
__global__ __launch_bounds__(256) void k_dualgemm(
    const float* __restrict__ A, const float* __restrict__ W1,
    const float* __restrict__ W2, const float* __restrict__ b1,
    const float* __restrict__ b2, const float* __restrict__ gvec,
    const int* __restrict__ cnt_send, float* __restrict__ outH,
    float* __restrict__ conv, int n) {
  __shared__ float As[128][BK + 1];  // +1 pad breaks write conflicts
  __shared__ float Ws[BK][D];
  const int t = threadIdx.x;
  const int variant = blockIdx.y;
  const float* __restrict__ W = variant ? W2 : W1;
  const int row0 = blockIdx.x * 128;
  const int tx = t & 15, ty = t >> 4;

  float acc[8][8];
#pragma unroll
  for (int i = 0; i < 8; ++i)
#pragma unroll
    for (int j = 0; j < 8; ++j) acc[i][j] = 0.f;

  for (int k0 = 0; k0 < D; k0 += BK) {
    // stage A tile: 128 rows x BK cols
    {
      const int lr = t >> 3;         // 0..31
      const int lk = (t & 7) * 4;    // 0,4,...,28
#pragma unroll
      for (int p = 0; p < 4; ++p) {
        const int rr = p * 32 + lr;
        const int row = row0 + rr;
        float4 v = make_float4(0.f, 0.f, 0.f, 0.f);
        if (row < n) v = *(const float4*)(A + (size_t)row * D + k0 + lk);
        As[rr][lk + 0] = v.x; As[rr][lk + 1] = v.y;
        As[rr][lk + 2] = v.z; As[rr][lk + 3] = v.w;
      }
    }
    // stage W slab: BK rows x 128 cols (b128-friendly, row stride 512B)
    {
      const int c4 = (t & 31) * 4;
      const int kk = t >> 5;  // 0..7
#pragma unroll
      for (int p = 0; p < 4; ++p) {
        const int k = p * 8 + kk;
        *(float4*)&Ws[k][c4] = *(const float4*)(W + (size_t)(k0 + k) * D + c4);
      }
    }
    __syncthreads();
#pragma unroll
    for (int k = 0; k < BK; ++k) {
      float a[8];
#pragma unroll
      for (int i = 0; i < 4; ++i) {
        a[i] = As[ty * 4 + i][k];           // broadcast within 16-lane phase
        a[4 + i] = As[64 + ty * 4 + i][k];
      }
      const float4 w0 = *(const float4*)&Ws[k][tx * 4];
      const float4 w1 = *(const float4*)&Ws[k][64 + tx * 4];
      const float w[8] = {w0.x, w0.y, w0.z, w0.w, w1.x, w1.y, w1.z, w1.w};
#pragma unroll
      for (int i = 0; i < 8; ++i)
#pragma unroll
        for (int j = 0; j < 8; ++j) acc[i][j] = fmaf(a[i], w[j], acc[i][j]);
    }
    __syncthreads();
  }

  const int c0 = tx * 4, c1 = 64 + tx * 4;
  if (variant == 0) {
    const float4 bb0 = *(const float4*)(b1 + c0);
    const float4 bb1 = *(const float4*)(b1 + c1);
    const float4 gg0 = *(const float4*)(gvec + c0);
    const float4 gg1 = *(const float4*)(gvec + c1);
#pragma unroll
    for (int i = 0; i < 8; ++i) {
      const int row = row0 + (i < 4 ? ty * 4 + i : 64 + ty * 4 + (i - 4));
      if (row >= n) continue;
      float4 v0 = make_float4(acc[i][0] + bb0.x + gg0.x, acc[i][1] + bb0.y + gg0.y,
                              acc[i][2] + bb0.z + gg0.z, acc[i][3] + bb0.w + gg0.w);
      float4 v1 = make_float4(acc[i][4] + bb1.x + gg1.x, acc[i][5] + bb1.y + gg1.y,
                              acc[i][6] + bb1.z + gg1.z, acc[i][7] + bb1.w + gg1.w);
      *(float4*)(outH + (size_t)row * D + c0) = v0;
      *(float4*)(outH + (size_t)row * D + c1) = v1;
    }
  } else {
    const float4 bb0 = *(const float4*)(b2 + c0);
    const float4 bb1 = *(const float4*)(b2 + c1);
#pragma unroll
    for (int i = 0; i < 8; ++i) {
      const int row = row0 + (i < 4 ? ty * 4 + i : 64 + ty * 4 + (i - 4));
      if (row >= n) continue;
      const float sc = rsqrtf(fmaxf((float)cnt_send[row], 1.f));
      float4 v0 = make_float4((acc[i][0] + bb0.x) * sc, (acc[i][1] + bb0.y) * sc,
                              (acc[i][2] + bb0.z) * sc, (acc[i][3] + bb0.w) * sc);
      float4 v1 = make_float4((acc[i][4] + bb1.x) * sc, (acc[i][5] + bb1.y) * sc,
                              (acc[i][6] + bb1.z) * sc, (acc[i][7] + bb1.w) * sc);
      *(float4*)(conv + (size_t)row * D + c0) = v0;
      *(float4*)(conv + (size_t)row * D + c1) = v1;
    }
  }
}

// K5: pull-style aggregation + fused epilogue. One wave owns one receiver row:
// gather conv[sender] rows (float2/lane), scale by rsqrt(recv_deg), add to the
// pre-staged h1 (already holds b1+gvec), ReLU, +nodes residual, write h, and
// accumulate the column-sum `an` in registers (one global atomic/col/block).
__global__ __launch_bounds__(256) void k_agg_finalize(
    const float* __restrict__ conv, const int* __restrict__ off,
    const int* __restrict__ cnt_recv, const int* __restrict__ srt,
    const float* __restrict__ nodes, float* __restrict__ h,
    float* __restrict__ an, int n) {
  __shared__ float anl[4][D];
  const int widx = threadIdx.x >> 6;
  const int lane = threadIdx.x & 63;
  const int gw = blockIdx.x * 4 + widx;
  const int nw = gridDim.x * 4;
  float ax = 0.f, ay = 0.f;
  for (int r = gw; r < n; r += nw) {
    const int dg = cnt_recv[r];
    const int o = off[r];
    float sx = 0.f, sy = 0.f;
    for (int i = 0; i < dg; ++i) {
      const int s = srt[o + i];  // wave-uniform -> scalar load
      const float2 c2 = *(const float2*)(conv + (size_t)s * D + lane * 2);
      sx += c2.x;
      sy += c2.y;
    }
    const float sc = rsqrtf(fmaxf((float)dg, 1.f));
    const float2 h1 = *(const float2*)(h + (size_t)r * D + lane * 2);
    const float2 nd = *(const float2*)(nodes + (size_t)r * D + lane * 2);
    const float x0 = fmaxf(h1.x + sx * sc, 0.f) + nd.x;
    const float x1 = fmaxf(h1.y + sy * sc, 0.f) + nd.y;
    *(float2*)(h + (size_t)r * D + lane * 2) = make_float2(x0, x1);
    ax += x0;
    ay += x1;
  }
  anl[widx][lane * 2] = ax;
  anl[widx][lane * 2 + 1] = ay;
  __syncthreads();
  if (threadIdx.x < D) {
    const float s = anl[0][threadIdx.x] + anl[1][threadIdx.x] +
                    anl[2][threadIdx.x] + anl[3][threadIdx.x];
    atomicAdd(an + threadIdx.x, s);
  }
}

// K6: g_new = globals + relu(concat([an, globals]) @ Wg + bg)
__global__ void k_gupdate(const float* __restrict__ an, const float* __restrict__ g,
                          const float* __restrict__ Wg, const float* __restrict__ bg,
                          float* __restrict__ gout) {
  const int j = threadIdx.x;
  float acc = bg[j];
  for (int k = 0; k < D; ++k) acc = fmaf(an[k], Wg[k * D + j], acc);
  for (int k = 0; k < D; ++k) acc = fmaf(g[k], Wg[(D + k) * D + j], acc);
  gout[j] = g[j] + fmaxf(acc, 0.f);
}

extern "C" void kernel_launch(void* const* d_in, const int* in_sizes, int n_in,
                              void* d_out, int out_size, void* d_ws, size_t ws_size,
                              hipStream_t stream) {
  const float* nodes = (const float*)d_in[0];
  const float* globals_ = (const float*)d_in[1];
  const int* senders = (const int*)d_in[2];
  const int* receivers = (const int*)d_in[3];
  const float* W1_w = (const float*)d_in[4];
  const float* W1_b = (const float*)d_in[5];
  const float* W2_w = (const float*)d_in[6];
  const float* W2_b = (const float*)d_in[7];
  const float* W3_w = (const float*)d_in[8];
  const float* W3_b = (const float*)d_in[9];
  const float* Wg_w = (const float*)d_in[10];
  const float* Wg_b = (const float*)d_in[11];
  const int N = in_sizes[0] / D;
  const int E = in_sizes[2];

  float* h = (float*)d_out;                 // [N, D]
  float* gout = h + (size_t)N * D;          // [D]

  // workspace layout (~55.4 MB total):
  float* ws = (float*)d_ws;
  float* conv = ws;                          // N*D floats
  int* cnt_send = (int*)(ws + (size_t)N * D);  // N
  int* cnt_recv = cnt_send + N;                // N
  int* off = cnt_recv + N;                     // N
  int* cursor = off + N;                       // N
  int* srt = cursor + N;                       // E
  float* gvec = (float*)(srt + E);             // D
  float* an = gvec + D;                        // D

  hipMemsetAsync(cnt_send, 0, 2 * (size_t)N * sizeof(int), stream);
  hipMemsetAsync(an, 0, D * sizeof(float), stream);

  hipLaunchKernelGGL(k_gproj, dim3(1), dim3(D), 0, stream, globals_, W3_w, W3_b, gvec);
  hipLaunchKernelGGL(k_degrees, dim3((E + 255) / 256), dim3(256), 0, stream,
                     senders, receivers, cnt_send, cnt_recv, E);
  hipLaunchKernelGGL(k_scan, dim3(1), dim3(1024), 0, stream, cnt_recv, off, cursor, N);
  hipLaunchKernelGGL(k_fill, dim3((E + 255) / 256), dim3(256), 0, stream,
                     senders, receivers, cursor, srt, E);
  hipLaunchKernelGGL(k_dualgemm, dim3((N + 127) / 128, 2), dim3(256), 0, stream,
                     nodes, W1_w, W2_w, W1_b, W2_b, gvec, cnt_send, h, conv, N);
  hipLaunchKernelGGL(k_agg_finalize, dim3(1024), dim3(256), 0, stream,
                     conv, off, cnt_recv, srt, nodes, h, an, N);
  hipLaunchKernelGGL(k_gupdate, dim3(1), dim3(D), 0, stream, an, globals_, Wg_w, Wg_b, gout);
}

// Round 2
// 406.985 us; speedup vs baseline: 1.2781x; 1.2781x over previous
//
#include <hip/hip_runtime.h>

#define D 128

typedef __attribute__((ext_vector_type(8))) short short8;
typedef __attribute__((ext_vector_type(4))) float floatx4;

// RNE split of fp32 into bf16 hi + bf16 lo (x ~= hi + lo, err ~2^-17 |x|)
__device__ inline void bf16split(float x, ushort& hi, ushort& lo) {
  unsigned u = __float_as_uint(x);
  unsigned rh = (u + 0x7FFFu + ((u >> 16) & 1u)) & 0xFFFF0000u;
  hi = (ushort)(rh >> 16);
  float fl = x - __uint_as_float(rh);
  unsigned ul = __float_as_uint(fl);
  lo = (ushort)((ul + 0x7FFFu + ((ul >> 16) & 1u)) >> 16);
}

// K0: gvec = globals @ W3 + b3
__global__ void k_gproj(const float* __restrict__ g, const float* __restrict__ W3,
                        const float* __restrict__ b3, float* __restrict__ gvec) {
  const int j = threadIdx.x;
  float acc = b3[j];
  for (int k = 0; k < D; ++k) acc = fmaf(g[k], W3[k * D + j], acc);
  gvec[j] = acc;
}

// K1: degree histograms
__global__ void k_degrees(const int* __restrict__ snd, const int* __restrict__ rcv,
                          int* __restrict__ cs, int* __restrict__ cr, int E) {
  const int e = blockIdx.x * blockDim.x + threadIdx.x;
  if (e < E) {
    atomicAdd(cs + snd[e], 1);
    atomicAdd(cr + rcv[e], 1);
  }
}

// K2: single-block exclusive scan in thread-ownership order
__global__ void k_scan(const int* __restrict__ cnt, int* __restrict__ off,
                       int* __restrict__ cursor, int n) {
  __shared__ int part[1024];
  const int t = threadIdx.x;
  int s = 0;
  for (int r = t; r < n; r += 1024) s += cnt[r];
  part[t] = s;
  __syncthreads();
  for (int st = 1; st < 1024; st <<= 1) {
    int v = (t >= st) ? part[t - st] : 0;
    __syncthreads();
    part[t] += v;
    __syncthreads();
  }
  int running = (t == 0) ? 0 : part[t - 1];
  for (int r = t; r < n; r += 1024) {
    off[r] = running;
    cursor[r] = running;
    running += cnt[r];
  }
}

// K3: CSR fill (bucket edges by receiver)
__global__ void k_fill(const int* __restrict__ snd, const int* __restrict__ rcv,
                       int* __restrict__ cursor, int* __restrict__ srt, int E) {
  const int e = blockIdx.x * blockDim.x + threadIdx.x;
  if (e < E) {
    const int p = atomicAdd(cursor + rcv[e], 1);
    srt[p] = snd[e];
  }
}

// K3b: precompute W^T split to bf16 hi/lo in global (once per call, 128KB).
// wt layout: [mat(2)][hi/lo(2)][n(128)][k(128)] ushorts
__global__ void k_wsplit(const float* __restrict__ W1, const float* __restrict__ W2,
                         ushort* __restrict__ wt) {
  const int id = blockIdx.x * blockDim.x + threadIdx.x;  // 2*16384
  const int mat = id >> 14;
  const int idx = id & 16383;
  const int k = idx >> 7;
  const int n = idx & 127;  // consecutive threads: coalesced read
  const float x = (mat ? W2 : W1)[k * D + n];
  ushort hi, lo;
  bf16split(x, hi, lo);
  wt[(size_t)mat * 32768 + (size_t)n * 128 + k] = hi;
  wt[(size_t)mat * 32768 + 16384 + (size_t)n * 128 + k] = lo;
}

// K4: bf16x3 MFMA dual GEMM. blockIdx.y selects variant:
//   0: outH = A@W1 + b1 + gvec          1: conv = (A@W2 + b2)*rsqrt(max(sdeg,1))
// 128x128 tile/block, 4 waves 2x2, 64x64/wave = 16 mfma_f32_16x16x32_bf16 tiles.
// K in two 64-passes; LDS exactly 64KB (2 blocks/CU). Chunk-XOR swizzle keeps
// b128 frag reads bank-balanced with zero row padding.
__global__ __launch_bounds__(256, 2) void k_dualgemm(
    const float* __restrict__ A, const ushort* __restrict__ wt,
    const float* __restrict__ b1, const float* __restrict__ b2,
    const float* __restrict__ gvec, const int* __restrict__ cnt_send,
    float* __restrict__ outH, float* __restrict__ conv, int n) {
  __shared__ ushort Ah[128 * 64], Al[128 * 64], Wh[128 * 64], Wl[128 * 64];
  const int t = threadIdx.x;
  const int variant = blockIdx.y;
  const int row0 = blockIdx.x * 128;
  const int lane = t & 63, widx = t >> 6;
  const int wr = widx >> 1, wc = widx & 1;
  const int m = lane & 15, quad = lane >> 4;
  const ushort* wtb = wt + (size_t)variant * 32768;

  floatx4 acc[4][4];
#pragma unroll
  for (int i = 0; i < 4; ++i)
#pragma unroll
    for (int j = 0; j < 4; ++j) acc[i][j] = (floatx4)0.f;

  const int srow = t >> 1, shalf = t & 1;  // staging coords

  for (int p = 0; p < 2; ++p) {
    // --- stage A (128 rows x 64 k fp32 -> bf16 hi/lo) ---
    {
      const int grow = row0 + srow;
      const bool ok = grow < n;
      const float* gp = A + (size_t)grow * D + p * 64 + shalf * 32;
#pragma unroll
      for (int c = 0; c < 8; ++c) {
        float4 v = make_float4(0.f, 0.f, 0.f, 0.f);
        if (ok) v = *(const float4*)(gp + 4 * c);
        ushort h0, l0, h1, l1, h2, l2, h3, l3;
        bf16split(v.x, h0, l0); bf16split(v.y, h1, l1);
        bf16split(v.z, h2, l2); bf16split(v.w, h3, l3);
        const int kl = shalf * 32 + 4 * c;
        const int ch = (kl >> 3) ^ (srow & 7);
        const int a = srow * 64 + ch * 8 + (kl & 7);
        *(ushort4*)&Ah[a] = make_ushort4(h0, h1, h2, h3);
        *(ushort4*)&Al[a] = make_ushort4(l0, l1, l2, l3);
      }
    }
    // --- stage W^T slab (128 n x 64 k bf16, from precomputed global) ---
    {
      const ushort* gh = wtb + (size_t)srow * 128 + p * 64 + shalf * 32;
      const ushort* gl = gh + 16384;
#pragma unroll
      for (int c = 0; c < 4; ++c) {
        const uint4 vh = *(const uint4*)(gh + 8 * c);
        const uint4 vl = *(const uint4*)(gl + 8 * c);
        const int ch = (shalf * 4 + c) ^ (srow & 7);
        const int a = srow * 64 + ch * 8;
        *(uint4*)&Wh[a] = vh;
        *(uint4*)&Wl[a] = vl;
      }
    }
    __syncthreads();
#pragma unroll
    for (int kk = 0; kk < 2; ++kk) {
      const int swz = (((kk << 2) + quad) ^ (lane & 7)) << 3;
      short8 a_h[4], a_l[4], b_h[4], b_l[4];
#pragma unroll
      for (int i = 0; i < 4; ++i) {
        const int r = (wr * 64 + i * 16 + m) * 64 + swz;
        a_h[i] = *(const short8*)&Ah[r];
        a_l[i] = *(const short8*)&Al[r];
      }
#pragma unroll
      for (int j = 0; j < 4; ++j) {
        const int r = (wc * 64 + j * 16 + m) * 64 + swz;
        b_h[j] = *(const short8*)&Wh[r];
        b_l[j] = *(const short8*)&Wl[r];
      }
#pragma unroll
      for (int i = 0; i < 4; ++i)
#pragma unroll
        for (int j = 0; j < 4; ++j) {
          floatx4 c = acc[i][j];
          c = __builtin_amdgcn_mfma_f32_16x16x32_bf16(a_h[i], b_h[j], c, 0, 0, 0);
          c = __builtin_amdgcn_mfma_f32_16x16x32_bf16(a_h[i], b_l[j], c, 0, 0, 0);
          c = __builtin_amdgcn_mfma_f32_16x16x32_bf16(a_l[i], b_h[j], c, 0, 0, 0);
          acc[i][j] = c;
        }
    }
    __syncthreads();
  }

  // --- epilogue: C/D layout col=lane&15, row=quad*4+reg ---
  if (variant == 0) {
    float bb[4], gg[4];
#pragma unroll
    for (int j = 0; j < 4; ++j) {
      const int col = wc * 64 + j * 16 + m;
      bb[j] = b1[col];
      gg[j] = gvec[col];
    }
#pragma unroll
    for (int i = 0; i < 4; ++i)
#pragma unroll
      for (int pp = 0; pp < 4; ++pp) {
        const int rg = row0 + wr * 64 + i * 16 + quad * 4 + pp;
        if (rg >= n) continue;
#pragma unroll
        for (int j = 0; j < 4; ++j) {
          const int col = wc * 64 + j * 16 + m;
          outH[(size_t)rg * D + col] = acc[i][j][pp] + bb[j] + gg[j];
        }
      }
  } else {
    float bb[4];
#pragma unroll
    for (int j = 0; j < 4; ++j) bb[j] = b2[wc * 64 + j * 16 + m];
#pragma unroll
    for (int i = 0; i < 4; ++i)
#pragma unroll
      for (int pp = 0; pp < 4; ++pp) {
        const int rg = row0 + wr * 64 + i * 16 + quad * 4 + pp;
        if (rg >= n) continue;
        const float sc = rsqrtf(fmaxf((float)cnt_send[rg], 1.f));
#pragma unroll
        for (int j = 0; j < 4; ++j) {
          const int col = wc * 64 + j * 16 + m;
          conv[(size_t)rg * D + col] = (acc[i][j][pp] + bb[j]) * sc;
        }
      }
  }
}

// K5: pull aggregation + fused epilogue, 4-deep load prefetch for MLP.
__global__ __launch_bounds__(256) void k_agg_finalize(
    const float* __restrict__ conv, const int* __restrict__ off,
    const int* __restrict__ cnt_recv, const int* __restrict__ srt,
    const float* __restrict__ nodes, float* __restrict__ h,
    float* __restrict__ an, int n) {
  __shared__ float anl[4][D];
  const int widx = threadIdx.x >> 6;
  const int lane = threadIdx.x & 63;
  const int gw = blockIdx.x * 4 + widx;
  const int nw = gridDim.x * 4;
  float ax = 0.f, ay = 0.f;
  for (int r = gw; r < n; r += nw) {
    const int dg = cnt_recv[r];
    const int o = off[r];
    float sx = 0.f, sy = 0.f;
    int i = 0;
    for (; i + 4 <= dg; i += 4) {
      const int s0 = srt[o + i], s1 = srt[o + i + 1];
      const int s2 = srt[o + i + 2], s3 = srt[o + i + 3];
      const float2 c0 = *(const float2*)(conv + (size_t)s0 * D + lane * 2);
      const float2 c1 = *(const float2*)(conv + (size_t)s1 * D + lane * 2);
      const float2 c2 = *(const float2*)(conv + (size_t)s2 * D + lane * 2);
      const float2 c3 = *(const float2*)(conv + (size_t)s3 * D + lane * 2);
      sx += (c0.x + c1.x) + (c2.x + c3.x);
      sy += (c0.y + c1.y) + (c2.y + c3.y);
    }
    for (; i < dg; ++i) {
      const int s = srt[o + i];
      const float2 c2v = *(const float2*)(conv + (size_t)s * D + lane * 2);
      sx += c2v.x;
      sy += c2v.y;
    }
    const float sc = rsqrtf(fmaxf((float)dg, 1.f));
    const float2 h1 = *(const float2*)(h + (size_t)r * D + lane * 2);
    const float2 nd = *(const float2*)(nodes + (size_t)r * D + lane * 2);
    const float x0 = fmaxf(h1.x + sx * sc, 0.f) + nd.x;
    const float x1 = fmaxf(h1.y + sy * sc, 0.f) + nd.y;
    *(float2*)(h + (size_t)r * D + lane * 2) = make_float2(x0, x1);
    ax += x0;
    ay += x1;
  }
  anl[widx][lane * 2] = ax;
  anl[widx][lane * 2 + 1] = ay;
  __syncthreads();
  if (threadIdx.x < D) {
    const float s = anl[0][threadIdx.x] + anl[1][threadIdx.x] +
                    anl[2][threadIdx.x] + anl[3][threadIdx.x];
    atomicAdd(an + threadIdx.x, s);
  }
}

// K6: g_new = globals + relu(concat([an, globals]) @ Wg + bg)
__global__ void k_gupdate(const float* __restrict__ an, const float* __restrict__ g,
                          const float* __restrict__ Wg, const float* __restrict__ bg,
                          float* __restrict__ gout) {
  const int j = threadIdx.x;
  float acc = bg[j];
  for (int k = 0; k < D; ++k) acc = fmaf(an[k], Wg[k * D + j], acc);
  for (int k = 0; k < D; ++k) acc = fmaf(g[k], Wg[(D + k) * D + j], acc);
  gout[j] = g[j] + fmaxf(acc, 0.f);
}

extern "C" void kernel_launch(void* const* d_in, const int* in_sizes, int n_in,
                              void* d_out, int out_size, void* d_ws, size_t ws_size,
                              hipStream_t stream) {
  const float* nodes = (const float*)d_in[0];
  const float* globals_ = (const float*)d_in[1];
  const int* senders = (const int*)d_in[2];
  const int* receivers = (const int*)d_in[3];
  const float* W1_w = (const float*)d_in[4];
  const float* W1_b = (const float*)d_in[5];
  const float* W2_w = (const float*)d_in[6];
  const float* W2_b = (const float*)d_in[7];
  const float* W3_w = (const float*)d_in[8];
  const float* W3_b = (const float*)d_in[9];
  const float* Wg_w = (const float*)d_in[10];
  const float* Wg_b = (const float*)d_in[11];
  const int N = in_sizes[0] / D;
  const int E = in_sizes[2];

  float* h = (float*)d_out;
  float* gout = h + (size_t)N * D;

  float* ws = (float*)d_ws;
  float* conv = ws;                            // N*D floats
  int* cnt_send = (int*)(ws + (size_t)N * D);  // N
  int* cnt_recv = cnt_send + N;                // N
  int* off = cnt_recv + N;                     // N
  int* cursor = off + N;                       // N (dead after k_fill -> reused for wt)
  int* srt = cursor + N;                       // E
  float* gvec = (float*)(srt + E);             // D
  float* an = gvec + D;                        // D
  ushort* wt = (ushort*)cursor;                // 4*16384 ushorts = 128KB <= N*4 bytes

  hipMemsetAsync(cnt_send, 0, 2 * (size_t)N * sizeof(int), stream);
  hipMemsetAsync(an, 0, D * sizeof(float), stream);

  hipLaunchKernelGGL(k_gproj, dim3(1), dim3(D), 0, stream, globals_, W3_w, W3_b, gvec);
  hipLaunchKernelGGL(k_degrees, dim3((E + 255) / 256), dim3(256), 0, stream,
                     senders, receivers, cnt_send, cnt_recv, E);
  hipLaunchKernelGGL(k_scan, dim3(1), dim3(1024), 0, stream, cnt_recv, off, cursor, N);
  hipLaunchKernelGGL(k_fill, dim3((E + 255) / 256), dim3(256), 0, stream,
                     senders, receivers, cursor, srt, E);
  hipLaunchKernelGGL(k_wsplit, dim3(128), dim3(256), 0, stream, W2_w == W2_w ? W1_w : W1_w, W2_w, wt);
  hipLaunchKernelGGL(k_dualgemm, dim3((N + 127) / 128, 2), dim3(256), 0, stream,
                     nodes, wt, W1_b, W2_b, gvec, cnt_send, h, conv, N);
  hipLaunchKernelGGL(k_agg_finalize, dim3(2048), dim3(256), 0, stream,
                     conv, off, cnt_recv, srt, nodes, h, an, N);
  hipLaunchKernelGGL(k_gupdate, dim3(1), dim3(D), 0, stream, an, globals_, Wg_w, Wg_b, gout);
}

// Round 3
// 387.757 us; speedup vs baseline: 1.3415x; 1.0496x over previous
//
#include <hip/hip_runtime.h>

#define D 128

typedef __attribute__((ext_vector_type(8))) short short8;
typedef __attribute__((ext_vector_type(4))) float floatx4;

// RNE split of fp32 into bf16 hi + bf16 lo (x ~= hi + lo, err ~2^-17 |x|)
__device__ inline void bf16split(float x, ushort& hi, ushort& lo) {
  unsigned u = __float_as_uint(x);
  unsigned rh = (u + 0x7FFFu + ((u >> 16) & 1u)) & 0xFFFF0000u;
  hi = (ushort)(rh >> 16);
  float fl = x - __uint_as_float(rh);
  unsigned ul = __float_as_uint(fl);
  lo = (ushort)((ul + 0x7FFFu + ((ul >> 16) & 1u)) >> 16);
}

// K0: gvec = globals @ W3 + b3
__global__ void k_gproj(const float* __restrict__ g, const float* __restrict__ W3,
                        const float* __restrict__ b3, float* __restrict__ gvec) {
  const int j = threadIdx.x;
  float acc = b3[j];
  for (int k = 0; k < D; ++k) acc = fmaf(g[k], W3[k * D + j], acc);
  gvec[j] = acc;
}

// K1: degree histograms
__global__ void k_degrees(const int* __restrict__ snd, const int* __restrict__ rcv,
                          int* __restrict__ cs, int* __restrict__ cr, int E) {
  const int e = blockIdx.x * blockDim.x + threadIdx.x;
  if (e < E) {
    atomicAdd(cs + snd[e], 1);
    atomicAdd(cr + rcv[e], 1);
  }
}

// K2: single-block exclusive scan in thread-ownership order
__global__ void k_scan(const int* __restrict__ cnt, int* __restrict__ off,
                       int* __restrict__ cursor, int n) {
  __shared__ int part[1024];
  const int t = threadIdx.x;
  int s = 0;
  for (int r = t; r < n; r += 1024) s += cnt[r];
  part[t] = s;
  __syncthreads();
  for (int st = 1; st < 1024; st <<= 1) {
    int v = (t >= st) ? part[t - st] : 0;
    __syncthreads();
    part[t] += v;
    __syncthreads();
  }
  int running = (t == 0) ? 0 : part[t - 1];
  for (int r = t; r < n; r += 1024) {
    off[r] = running;
    cursor[r] = running;
    running += cnt[r];
  }
}

// K3: CSR fill (bucket edges by receiver)
__global__ void k_fill(const int* __restrict__ snd, const int* __restrict__ rcv,
                       int* __restrict__ cursor, int* __restrict__ srt, int E) {
  const int e = blockIdx.x * blockDim.x + threadIdx.x;
  if (e < E) {
    const int p = atomicAdd(cursor + rcv[e], 1);
    srt[p] = snd[e];
  }
}

// K3b: precompute W^T split to bf16 hi/lo in global (once per call, 128KB).
// wt layout: [mat(2)][hi/lo(2)][n(128)][k(128)] ushorts
__global__ void k_wsplit(const float* __restrict__ W1, const float* __restrict__ W2,
                         ushort* __restrict__ wt) {
  const int id = blockIdx.x * blockDim.x + threadIdx.x;  // 2*16384
  const int mat = id >> 14;
  const int idx = id & 16383;
  const int k = idx >> 7;
  const int n = idx & 127;  // consecutive threads: coalesced read
  const float x = (mat ? W2 : W1)[k * D + n];
  ushort hi, lo;
  bf16split(x, hi, lo);
  wt[(size_t)mat * 32768 + (size_t)n * 128 + k] = hi;
  wt[(size_t)mat * 32768 + 16384 + (size_t)n * 128 + k] = lo;
}

// K4: bf16x3 MFMA dual GEMM. blockIdx.y selects variant:
//   0: outH = A@W1 + b1 + gvec          1: conv = (A@W2 + b2)*rsqrt(max(sdeg,1))
// 128x128 tile/block, 4 waves 2x2, 64x64/wave = 16 mfma_f32_16x16x32_bf16 tiles.
__global__ __launch_bounds__(256, 2) void k_dualgemm(
    const float* __restrict__ A, const ushort* __restrict__ wt,
    const float* __restrict__ b1, const float* __restrict__ b2,
    const float* __restrict__ gvec, const int* __restrict__ cnt_send,
    float* __restrict__ outH, float* __restrict__ conv, int n) {
  __shared__ ushort Ah[128 * 64], Al[128 * 64], Wh[128 * 64], Wl[128 * 64];
  const int t = threadIdx.x;
  const int variant = blockIdx.y;
  const int row0 = blockIdx.x * 128;
  const int lane = t & 63, widx = t >> 6;
  const int wr = widx >> 1, wc = widx & 1;
  const int m = lane & 15, quad = lane >> 4;
  const ushort* wtb = wt + (size_t)variant * 32768;

  floatx4 acc[4][4];
#pragma unroll
  for (int i = 0; i < 4; ++i)
#pragma unroll
    for (int j = 0; j < 4; ++j) acc[i][j] = (floatx4)0.f;

  const int srow = t >> 1, shalf = t & 1;  // staging coords

  for (int p = 0; p < 2; ++p) {
    // --- stage A (128 rows x 64 k fp32 -> bf16 hi/lo) ---
    {
      const int grow = row0 + srow;
      const bool ok = grow < n;
      const float* gp = A + (size_t)grow * D + p * 64 + shalf * 32;
#pragma unroll
      for (int c = 0; c < 8; ++c) {
        float4 v = make_float4(0.f, 0.f, 0.f, 0.f);
        if (ok) v = *(const float4*)(gp + 4 * c);
        ushort h0, l0, h1, l1, h2, l2, h3, l3;
        bf16split(v.x, h0, l0); bf16split(v.y, h1, l1);
        bf16split(v.z, h2, l2); bf16split(v.w, h3, l3);
        const int kl = shalf * 32 + 4 * c;
        const int ch = (kl >> 3) ^ (srow & 7);
        const int a = srow * 64 + ch * 8 + (kl & 7);
        *(ushort4*)&Ah[a] = make_ushort4(h0, h1, h2, h3);
        *(ushort4*)&Al[a] = make_ushort4(l0, l1, l2, l3);
      }
    }
    // --- stage W^T slab (128 n x 64 k bf16, from precomputed global) ---
    {
      const ushort* gh = wtb + (size_t)srow * 128 + p * 64 + shalf * 32;
      const ushort* gl = gh + 16384;
#pragma unroll
      for (int c = 0; c < 4; ++c) {
        const uint4 vh = *(const uint4*)(gh + 8 * c);
        const uint4 vl = *(const uint4*)(gl + 8 * c);
        const int ch = (shalf * 4 + c) ^ (srow & 7);
        const int a = srow * 64 + ch * 8;
        *(uint4*)&Wh[a] = vh;
        *(uint4*)&Wl[a] = vl;
      }
    }
    __syncthreads();
#pragma unroll
    for (int kk = 0; kk < 2; ++kk) {
      const int swz = (((kk << 2) + quad) ^ (lane & 7)) << 3;
      short8 a_h[4], a_l[4], b_h[4], b_l[4];
#pragma unroll
      for (int i = 0; i < 4; ++i) {
        const int r = (wr * 64 + i * 16 + m) * 64 + swz;
        a_h[i] = *(const short8*)&Ah[r];
        a_l[i] = *(const short8*)&Al[r];
      }
#pragma unroll
      for (int j = 0; j < 4; ++j) {
        const int r = (wc * 64 + j * 16 + m) * 64 + swz;
        b_h[j] = *(const short8*)&Wh[r];
        b_l[j] = *(const short8*)&Wl[r];
      }
#pragma unroll
      for (int i = 0; i < 4; ++i)
#pragma unroll
        for (int j = 0; j < 4; ++j) {
          floatx4 c = acc[i][j];
          c = __builtin_amdgcn_mfma_f32_16x16x32_bf16(a_h[i], b_h[j], c, 0, 0, 0);
          c = __builtin_amdgcn_mfma_f32_16x16x32_bf16(a_h[i], b_l[j], c, 0, 0, 0);
          c = __builtin_amdgcn_mfma_f32_16x16x32_bf16(a_l[i], b_h[j], c, 0, 0, 0);
          acc[i][j] = c;
        }
    }
    __syncthreads();
  }

  // --- epilogue: C/D layout col=lane&15, row=quad*4+reg ---
  if (variant == 0) {
    float bb[4], gg[4];
#pragma unroll
    for (int j = 0; j < 4; ++j) {
      const int col = wc * 64 + j * 16 + m;
      bb[j] = b1[col];
      gg[j] = gvec[col];
    }
#pragma unroll
    for (int i = 0; i < 4; ++i)
#pragma unroll
      for (int pp = 0; pp < 4; ++pp) {
        const int rg = row0 + wr * 64 + i * 16 + quad * 4 + pp;
        if (rg >= n) continue;
#pragma unroll
        for (int j = 0; j < 4; ++j) {
          const int col = wc * 64 + j * 16 + m;
          outH[(size_t)rg * D + col] = acc[i][j][pp] + bb[j] + gg[j];
        }
      }
  } else {
    float bb[4];
#pragma unroll
    for (int j = 0; j < 4; ++j) bb[j] = b2[wc * 64 + j * 16 + m];
#pragma unroll
    for (int i = 0; i < 4; ++i)
#pragma unroll
      for (int pp = 0; pp < 4; ++pp) {
        const int rg = row0 + wr * 64 + i * 16 + quad * 4 + pp;
        if (rg >= n) continue;
        const float sc = rsqrtf(fmaxf((float)cnt_send[rg], 1.f));
#pragma unroll
        for (int j = 0; j < 4; ++j) {
          const int col = wc * 64 + j * 16 + m;
          conv[(size_t)rg * D + col] = (acc[i][j][pp] + bb[j]) * sc;
        }
      }
  }
}

// K5: pull aggregation + fused epilogue, v2.
// Half-wave (32 lanes) per receiver row, float4/lane; masked unroll-8 edge loop
// keeps 8 independent 16B gathers in flight even at avg degree 6.4 (invalid
// slots clamp to srt[o] -- an already-hot line -- and are masked from the sum).
__global__ __launch_bounds__(256) void k_agg_finalize(
    const float* __restrict__ conv, const int* __restrict__ off,
    const int* __restrict__ cnt_recv, const int* __restrict__ srt,
    const float* __restrict__ nodes, float* __restrict__ h,
    float* __restrict__ an, int n) {
  __shared__ float anl[8][D];
  const int hw = threadIdx.x >> 5;  // half-wave id 0..7
  const int ln = threadIdx.x & 31;  // lane in half-wave
  const int ghw = blockIdx.x * 8 + hw;
  const int nhw = gridDim.x * 8;
  const int c0 = ln * 4;

  float a0 = 0.f, a1 = 0.f, a2 = 0.f, a3 = 0.f;  // an partial (my 4 cols)
  for (int r = ghw; r < n; r += nhw) {
    const int dg = cnt_recv[r];
    const int o = off[r];
    // hoist epilogue loads to overlap with the gather
    const float4 h1 = *(const float4*)(h + (size_t)r * D + c0);
    const float4 nd = *(const float4*)(nodes + (size_t)r * D + c0);
    float sx = 0.f, sy = 0.f, sz = 0.f, sw = 0.f;
    for (int i = 0; i < dg; i += 8) {
      int idx[8];
      float mk[8];
#pragma unroll
      for (int j = 0; j < 8; ++j) {
        const int p = i + j;
        const bool v = p < dg;
        idx[j] = srt[o + (v ? p : 0)];
        mk[j] = v ? 1.f : 0.f;
      }
      float4 c[8];
#pragma unroll
      for (int j = 0; j < 8; ++j)
        c[j] = *(const float4*)(conv + (size_t)idx[j] * D + c0);
#pragma unroll
      for (int j = 0; j < 8; ++j) {
        sx = fmaf(mk[j], c[j].x, sx);
        sy = fmaf(mk[j], c[j].y, sy);
        sz = fmaf(mk[j], c[j].z, sz);
        sw = fmaf(mk[j], c[j].w, sw);
      }
    }
    const float sc = rsqrtf(fmaxf((float)dg, 1.f));
    const float x0 = fmaxf(h1.x + sx * sc, 0.f) + nd.x;
    const float x1 = fmaxf(h1.y + sy * sc, 0.f) + nd.y;
    const float x2 = fmaxf(h1.z + sz * sc, 0.f) + nd.z;
    const float x3 = fmaxf(h1.w + sw * sc, 0.f) + nd.w;
    *(float4*)(h + (size_t)r * D + c0) = make_float4(x0, x1, x2, x3);
    a0 += x0; a1 += x1; a2 += x2; a3 += x3;
  }
  anl[hw][c0 + 0] = a0;
  anl[hw][c0 + 1] = a1;
  anl[hw][c0 + 2] = a2;
  anl[hw][c0 + 3] = a3;
  __syncthreads();
  if (threadIdx.x < D) {
    float s = 0.f;
#pragma unroll
    for (int k = 0; k < 8; ++k) s += anl[k][threadIdx.x];
    atomicAdd(an + threadIdx.x, s);
  }
}

// K6: g_new = globals + relu(concat([an, globals]) @ Wg + bg)
__global__ void k_gupdate(const float* __restrict__ an, const float* __restrict__ g,
                          const float* __restrict__ Wg, const float* __restrict__ bg,
                          float* __restrict__ gout) {
  const int j = threadIdx.x;
  float acc = bg[j];
  for (int k = 0; k < D; ++k) acc = fmaf(an[k], Wg[k * D + j], acc);
  for (int k = 0; k < D; ++k) acc = fmaf(g[k], Wg[(D + k) * D + j], acc);
  gout[j] = g[j] + fmaxf(acc, 0.f);
}

extern "C" void kernel_launch(void* const* d_in, const int* in_sizes, int n_in,
                              void* d_out, int out_size, void* d_ws, size_t ws_size,
                              hipStream_t stream) {
  const float* nodes = (const float*)d_in[0];
  const float* globals_ = (const float*)d_in[1];
  const int* senders = (const int*)d_in[2];
  const int* receivers = (const int*)d_in[3];
  const float* W1_w = (const float*)d_in[4];
  const float* W1_b = (const float*)d_in[5];
  const float* W2_w = (const float*)d_in[6];
  const float* W2_b = (const float*)d_in[7];
  const float* W3_w = (const float*)d_in[8];
  const float* W3_b = (const float*)d_in[9];
  const float* Wg_w = (const float*)d_in[10];
  const float* Wg_b = (const float*)d_in[11];
  const int N = in_sizes[0] / D;
  const int E = in_sizes[2];

  float* h = (float*)d_out;
  float* gout = h + (size_t)N * D;

  float* ws = (float*)d_ws;
  float* conv = ws;                            // N*D floats
  int* cnt_send = (int*)(ws + (size_t)N * D);  // N
  int* cnt_recv = cnt_send + N;                // N
  int* off = cnt_recv + N;                     // N
  int* cursor = off + N;                       // N (dead after k_fill -> reused for wt)
  int* srt = cursor + N;                       // E
  float* gvec = (float*)(srt + E);             // D
  float* an = gvec + D;                        // D
  ushort* wt = (ushort*)cursor;                // 4*16384 ushorts = 128KB <= N*4 bytes

  hipMemsetAsync(cnt_send, 0, 2 * (size_t)N * sizeof(int), stream);
  hipMemsetAsync(an, 0, D * sizeof(float), stream);

  hipLaunchKernelGGL(k_gproj, dim3(1), dim3(D), 0, stream, globals_, W3_w, W3_b, gvec);
  hipLaunchKernelGGL(k_degrees, dim3((E + 255) / 256), dim3(256), 0, stream,
                     senders, receivers, cnt_send, cnt_recv, E);
  hipLaunchKernelGGL(k_scan, dim3(1), dim3(1024), 0, stream, cnt_recv, off, cursor, N);
  hipLaunchKernelGGL(k_fill, dim3((E + 255) / 256), dim3(256), 0, stream,
                     senders, receivers, cursor, srt, E);
  hipLaunchKernelGGL(k_wsplit, dim3(128), dim3(256), 0, stream, W1_w, W2_w, wt);
  hipLaunchKernelGGL(k_dualgemm, dim3((N + 127) / 128, 2), dim3(256), 0, stream,
                     nodes, wt, W1_b, W2_b, gvec, cnt_send, h, conv, N);
  hipLaunchKernelGGL(k_agg_finalize, dim3(2048), dim3(256), 0, stream,
                     conv, off, cnt_recv, srt, nodes, h, an, N);
  hipLaunchKernelGGL(k_gupdate, dim3(1), dim3(D), 0, stream, an, globals_, Wg_w, Wg_b, gout);
}